// Round 7
// baseline (1004.161 us; speedup 1.0000x reference)
//
#include <hip/hip_runtime.h>
#include <hip/hip_bf16.h>

typedef __hip_bfloat16 bf16;
typedef __attribute__((ext_vector_type(8))) short sh8;
typedef __attribute__((ext_vector_type(4))) short sh4;
typedef __attribute__((ext_vector_type(4))) float f32x4;

#define HWp 4800
#define Wd 80
#define Hd 60
#define Fh 64
#define Bn 4
#define Tn 12
#define KYS 5248               // 82*64 shorts per ky plane
#define sHT ((long)Fh*HWp)     // one [p][fo] image in shorts / [fo][p] in f32
#define ZT  ((long)Fh*HWp*4)   // per-t z stride in shorts (gate-packed)

__device__ __forceinline__ float b2f(bf16 v){ return __bfloat162float(v); }
__device__ __forceinline__ bf16 f2b(float v){ return __float2bfloat16(v); }
__device__ __forceinline__ float bits2f(short s){
    return __uint_as_float(((unsigned)(unsigned short)s) << 16);
}
__device__ __forceinline__ short f2bits(float f){
    bf16 t = f2b(f); short s; __builtin_memcpy(&s, &t, 2); return s;
}

// ---------------- weight prep ----------------
__global__ void perm_w_kernel(const float* __restrict__ src, float* __restrict__ dst, int cin){
    int idx = blockIdx.x*256 + threadIdx.x;
    int n = 256*cin*9;
    if (idx >= n) return;
    int co = idx/(cin*9); int r = idx - co*(cin*9);
    int g = co >> 6, fo = co & 63;
    dst[(fo*4+g)*cin*9 + r] = src[idx];
}
__global__ void perm_bias_kernel(const float* __restrict__ src, float* __restrict__ dst){
    int idx = threadIdx.x; // 256
    int g = idx >> 6, fo = idx & 63;
    dst[fo*4+g] = src[idx];
}
// U/W2 [256co][64ci][3][3] f32 -> bf16 MFMA A-fragments
__global__ void pack_w_kernel(const float* __restrict__ U, short* __restrict__ Apk){
    int d = blockIdx.x*256 + threadIdx.x;
    if (d >= 147456) return;
    int j = d & 7, l = (d>>3) & 63, ct = (d>>9) & 15, oc = d >> 13;
    int o = oc >> 1, cc = oc & 1;
    int co = ct*16 + (l & 15);
    int ci = cc*32 + (l>>4)*8 + j;
    Apk[d] = f2bits(U[(co*Fh + ci)*9 + o]);
}

// ---------------- small utils ----------------
__global__ void copy_f32_kernel(const float* __restrict__ src, float* __restrict__ dst, int n){
    int idx = blockIdx.x*256+threadIdx.x;
    if (idx < n) dst[idx] = src[idx];
}
__global__ void copy_h_f32_kernel(const float* __restrict__ src, long bstride, float* __restrict__ dst){
    long idx = (long)blockIdx.x*256+threadIdx.x;
    long n = (long)Bn*Fh*HWp;
    if (idx >= n) return;
    long b = idx/(Fh*HWp); long r = idx - b*(Fh*HWp);
    dst[idx] = src[b*bstride + r];
}
// f32 std [b][fo][p] -> bf16 channel-last [b][p][fo]
__global__ void h0cl_kernel(const float* __restrict__ src, bf16* __restrict__ dst){
    long idx = (long)blockIdx.x*256 + threadIdx.x;
    if (idx >= (long)Bn*Fh*HWp) return;
    int fo = (int)(idx & 63);
    long rest = idx >> 6;
    int p = (int)(rest % HWp);
    int b = (int)(rest / HWp);
    dst[idx] = f2b(src[((long)b*Fh + fo)*HWp + p]);
}

// ---------------- layer-1 input conv (CIN=4, VALU) ----------------
// z out: [b][t][fo][p][g] gate-packed, p fast => coalesced sh4 writes
__global__ void zx1_kernel(const float* __restrict__ xin,  // [B*T][4][HW]
                           const float* __restrict__ Wf,   // [64fo][4g][4ci][9]
                           const float* __restrict__ bias, // [64fo][4g]
                           short* __restrict__ zx)
{
    int p = blockIdx.x*blockDim.x + threadIdx.x;
    if (p >= HWp) return;
    int fo = blockIdx.y, bt = blockIdx.z;
    int y = p / Wd, x = p - y*Wd;
    const float* wf = Wf + fo*4*4*9;
    float acc[4] = {bias[fo*4+0], bias[fo*4+1], bias[fo*4+2], bias[fo*4+3]};
    int ym = (y > 0 ? y-1 : 0)*Wd, y0 = y*Wd, yp = (y < Hd-1 ? y+1 : Hd-1)*Wd;
    int xm = (x > 0 ? x-1 : 0),    xp = (x < Wd-1 ? x+1 : Wd-1);
    for (int ci = 0; ci < 4; ++ci){
        const float* ic = xin + ((long)bt*4 + ci)*HWp;
        float v[9];
        v[0]=ic[ym+xm]; v[1]=ic[ym+x]; v[2]=ic[ym+xp];
        v[3]=ic[y0+xm]; v[4]=ic[y0+x]; v[5]=ic[y0+xp];
        v[6]=ic[yp+xm]; v[7]=ic[yp+x]; v[8]=ic[yp+xp];
        #pragma unroll
        for (int g = 0; g < 4; ++g){
            const float* w = wf + (g*4+ci)*9;
            acc[g] += v[0]*w[0]+v[1]*w[1]+v[2]*w[2]
                    + v[3]*w[3]+v[4]*w[4]+v[5]*w[5]
                    + v[6]*w[6]+v[7]*w[7]+v[8]*w[8];
        }
    }
    sh4 o4 = { f2bits(acc[0]), f2bits(acc[1]), f2bits(acc[2]), f2bits(acc[3]) };
    *(sh4*)(zx + (((long)bt*Fh + fo)*HWp + p)*4) = o4;
}

// ---------------- channel-last LDS stage ----------------
// LDS lt[3][82][64]; chunk (x_l, cc) at x_l*64 + ((cc^(x_l&7))*8)
template<bool CLAMP, int NT>
__device__ __forceinline__ void stage_cl(const short* __restrict__ src, int y, short* lt){
    const int tid = threadIdx.x;
    for (int n = tid; n < 1968; n += NT){
        int row = n/656, rem = n - row*656;
        int rg = y + row - 1;
        bool rvalid = CLAMP ? true : (rg >= 0 && rg < Hd);
        rg = min(max(rg,0), Hd-1);
        int xg, cc, xl; bool cvalid = true;
        if (rem < 640){ xg = rem>>3; cc = rem&7; xl = xg+1; }
        else if (rem < 648){ xg = 0; cc = rem-640; xl = 0; cvalid = CLAMP; }
        else { xg = Wd-1; cc = rem-648; xl = 81; cvalid = CLAMP; }
        sh8 v = {0,0,0,0,0,0,0,0};
        if (rvalid && cvalid) v = *(const sh8*)(src + ((long)(rg*Wd + xg)*64 + cc*8));
        *(sh8*)(lt + row*KYS + xl*64 + ((cc ^ (xl&7))<<3)) = v;
    }
}

// 4-wave gemm core (zx_mfma): wave wv covers co-tiles {g*4+wv}
__device__ __forceinline__ void gemm_core(const short* __restrict__ Apk, const short* lt,
                                          int wv, int lane, f32x4 acc[4][5]){
    const int lane15 = lane & 15, grp = lane >> 4;
    #pragma unroll
    for (int o = 0; o < 9; ++o){
        int ky = o/3, kx = o - 3*(o/3);
        const short* lk = lt + ky*KYS;
        #pragma unroll
        for (int c = 0; c < 2; ++c){
            sh8 bfr[5];
            #pragma unroll
            for (int pt = 0; pt < 5; ++pt){
                int xl = pt*16 + lane15 + kx;
                int cc = (c*4 + grp) ^ (xl & 7);
                bfr[pt] = *(const sh8*)(lk + xl*64 + cc*8);
            }
            const short* ab = Apk + ((long)((o*2 + c)*16 + wv))*512 + lane*8;
            #pragma unroll
            for (int g = 0; g < 4; ++g){
                sh8 af = *(const sh8*)(ab + (long)g*4*512);
                #pragma unroll
                for (int pt = 0; pt < 5; ++pt)
                    acc[g][pt] = __builtin_amdgcn_mfma_f32_16x16x32_bf16(af, bfr[pt], acc[g][pt], 0, 0, 0);
            }
        }
    }
}

// ---------------- one LSTM timestep ----------------
// grid (Hd, Bn, 2); 128 threads = 2 waves; block covers fo in [fh*32, fh*32+32)
// hprev/hout: [b][p][fo] bf16; z: [b][t][fo][p][g]; c: [b][fo][p] f32; fx: [fo][p] f32 (+b stride)
template<bool WRITE_FX>
__global__ __launch_bounds__(128) void rec_step(
    const bf16* __restrict__ hprev, long h_bstride,
    const short* __restrict__ Upk,
    const short* __restrict__ zx_t, long z_bstride,
    float* __restrict__ c,
    bf16* __restrict__ hout,
    float* __restrict__ fx, long f_bstride)
{
    __shared__ short lt[3*KYS];
    __shared__ short lo[80*36];     // 80 px x 32 fo (stride 36)
    int y = blockIdx.x, b = blockIdx.y, fh = blockIdx.z;
    int tid = threadIdx.x, lane = tid & 63, wv = tid >> 6;
    int lane15 = lane & 15, grp = lane >> 4;
    int ft = fh*2 + wv;             // fo-tile 0..3

    stage_cl<false,128>((const short*)hprev + (long)b*h_bstride, y, lt);

    // prefetch z (gate-packed, coalesced 128B segments) and c
    sh4 zq[5][4]; float cold[5][4];
    const short* zb = zx_t + (long)b*z_bstride;
    #pragma unroll
    for (int pt = 0; pt < 5; ++pt){
        int p = y*Wd + pt*16 + lane15;
        #pragma unroll
        for (int r = 0; r < 4; ++r){
            int fo = ft*16 + grp*4 + r;
            zq[pt][r] = *(const sh4*)(zb + ((long)fo*HWp + p)*4);
            cold[pt][r] = c[((long)b*Fh + fo)*HWp + p];
        }
    }
    __syncthreads();

    f32x4 acc[4][5];
    #pragma unroll
    for (int g = 0; g < 4; ++g)
        #pragma unroll
        for (int pt = 0; pt < 5; ++pt) acc[g][pt] = (f32x4){0.f,0.f,0.f,0.f};

    #pragma unroll
    for (int o = 0; o < 9; ++o){
        int ky = o/3, kx = o - 3*(o/3);
        const short* lk = lt + ky*KYS;
        #pragma unroll
        for (int cch = 0; cch < 2; ++cch){
            sh8 bfr[5];
            #pragma unroll
            for (int pt = 0; pt < 5; ++pt){
                int xl = pt*16 + lane15 + kx;
                int cc = (cch*4 + grp) ^ (xl & 7);
                bfr[pt] = *(const sh8*)(lk + xl*64 + cc*8);
            }
            const short* ab = Upk + ((long)((o*2 + cch)*16 + ft))*512 + lane*8;
            #pragma unroll
            for (int g = 0; g < 4; ++g){
                sh8 af = *(const sh8*)(ab + (long)g*4*512);   // co-tile = g*4 + ft
                #pragma unroll
                for (int pt = 0; pt < 5; ++pt)
                    acc[g][pt] = __builtin_amdgcn_mfma_f32_16x16x32_bf16(af, bfr[pt], acc[g][pt], 0, 0, 0);
            }
        }
    }

    #pragma unroll
    for (int pt = 0; pt < 5; ++pt){
        int pl = pt*16 + lane15;
        int p = y*Wd + pl;
        #pragma unroll
        for (int r = 0; r < 4; ++r){
            int fo = ft*16 + grp*4 + r;
            float zi = acc[0][pt][r] + bits2f(zq[pt][r][0]);
            float zf = acc[1][pt][r] + bits2f(zq[pt][r][1]);
            float zg = acc[2][pt][r] + bits2f(zq[pt][r][2]);
            float zo = acc[3][pt][r] + bits2f(zq[pt][r][3]);
            float gi = fminf(fmaxf(0.2f*zi+0.5f, 0.f), 1.f);
            float gf = fminf(fmaxf(0.2f*zf+0.5f, 0.f), 1.f);
            float go = fminf(fmaxf(0.2f*zo+0.5f, 0.f), 1.f);
            float sg = 1.f/(1.f+__expf(-zg));
            float cn = gf*cold[pt][r] + gi*sg;
            float hn = go * (1.f/(1.f+__expf(-cn)));
            c[((long)b*Fh + fo)*HWp + p] = cn;
            lo[pl*36 + wv*16 + grp*4 + r] = f2bits(hn);
            if (WRITE_FX)
                fx[(long)b*f_bstride + (long)fo*HWp + p] = hn;
        }
    }
    __syncthreads();
    // coalesced flush: 80 px x 32 fo -> hout (64B-aligned sh4 segments)
    short* hb = (short*)hout + (long)b*sHT;
    #pragma unroll
    for (int k = 0; k < 5; ++k){
        int e = k*128 + tid;           // 0..639
        int pl = e >> 3, f4 = (e & 7)*4;
        sh4 hv = *(const sh4*)(lo + pl*36 + f4);
        *(sh4*)(hb + (long)(y*Wd + pl)*64 + fh*32 + f4) = hv;
    }
}

// ---------------- layer-2 input conv (MFMA, clamp pad) ----------------
__global__ __launch_bounds__(256,2) void zx_mfma(
    const bf16* __restrict__ x1,     // [t][b][p][fo] cl bf16
    const short* __restrict__ Wpk,
    const float* __restrict__ bias,  // [256] co = g*64+fo
    short* __restrict__ zxb)         // [b][t][fo][p][g]
{
    __shared__ short lt[3*KYS];
    int y = blockIdx.x, img = blockIdx.y;   // img = t*Bn + b
    int t = img / Bn, b = img - t*Bn;
    int tid = threadIdx.x, lane = tid & 63, wv = tid >> 6;
    int lane15 = lane & 15, grp = lane >> 4;
    stage_cl<true,256>((const short*)x1 + (long)img*sHT, y, lt);
    __syncthreads();
    f32x4 acc[4][5];
    #pragma unroll
    for (int g = 0; g < 4; ++g)
        #pragma unroll
        for (int pt = 0; pt < 5; ++pt) acc[g][pt] = (f32x4){0.f,0.f,0.f,0.f};
    gemm_core(Wpk, lt, wv, lane, acc);
    short* zb = zxb + ((long)(b*Tn + t))*ZT;
    #pragma unroll
    for (int pt = 0; pt < 5; ++pt){
        int p = y*Wd + pt*16 + lane15;
        #pragma unroll
        for (int r = 0; r < 4; ++r){
            int fo = wv*16 + grp*4 + r;
            sh4 o4 = { f2bits(acc[0][pt][r] + bias[fo]),
                       f2bits(acc[1][pt][r] + bias[64+fo]),
                       f2bits(acc[2][pt][r] + bias[128+fo]),
                       f2bits(acc[3][pt][r] + bias[192+fo]) };
            *(sh4*)(zb + ((long)fo*HWp + p)*4) = o4;
        }
    }
}

// ---------------- BatchNorm (channel-last x1) ----------------
#define BN_GRID 480
__global__ void bn_sum_cl(const short* __restrict__ x, float* __restrict__ sums){
    __shared__ float ls[160];
    int tid = threadIdx.x;
    if (tid < 160) ls[tid] = 0.f;
    __syncthreads();
    long gid = (long)blockIdx.x*256 + tid;
    const long nchunk = (long)Bn*Tn*HWp*8;   // sh8 chunks
    float s = 0.f, q = 0.f;
    for (long ch = gid; ch < nchunk; ch += (long)BN_GRID*256){
        sh8 v = *(const sh8*)(x + ch*8);
        #pragma unroll
        for (int j = 0; j < 8; ++j){ float f = bits2f(v[j]); s += f; q += f*f; }
    }
    int w = (int)((gid>>3) % Wd);   // constant along stride
    atomicAdd(&ls[w], s); atomicAdd(&ls[80+w], q);
    __syncthreads();
    if (tid < 160) atomicAdd(&sums[tid], ls[tid]);
}
__global__ void bn_coef_kernel(const float* __restrict__ sums, const float* __restrict__ g,
                               const float* __restrict__ bt, float* __restrict__ coef){
    int w = threadIdx.x; // 80
    const float N = (float)(Bn*Tn*Fh*Hd);
    float mean = sums[w]/N;
    float var  = sums[80+w]/N - mean*mean;
    float sc = rsqrtf(var + 1e-3f)*g[w];
    coef[w] = sc;
    coef[80+w] = bt[w] - mean*sc;
}
__global__ void bn_apply_cl(short* __restrict__ x, const float* __restrict__ coef){
    long gid = (long)blockIdx.x*256 + threadIdx.x;
    const long nchunk = (long)Bn*Tn*HWp*8;
    int w = (int)((gid>>3) % Wd);
    float sc = coef[w], sh = coef[80+w];
    for (long ch = gid; ch < nchunk; ch += (long)BN_GRID*256){
        sh8 v = *(sh8*)(x + ch*8);
        #pragma unroll
        for (int j = 0; j < 8; ++j) v[j] = f2bits(bits2f(v[j])*sc + sh);
        *(sh8*)(x + ch*8) = v;
    }
}

extern "C" void kernel_launch(void* const* d_in, const int* in_sizes, int n_in,
                              void* d_out, int out_size, void* d_ws, size_t ws_size,
                              hipStream_t stream){
    const float* xin  = (const float*)d_in[0];
    const float* h1_0 = (const float*)d_in[1];
    const float* c1_0 = (const float*)d_in[2];
    const float* h2_0 = (const float*)d_in[3];
    const float* c2_0 = (const float*)d_in[4];
    const float* W1   = (const float*)d_in[5];
    const float* U1   = (const float*)d_in[6];
    const float* b1   = (const float*)d_in[7];
    const float* W2   = (const float*)d_in[8];
    const float* U2   = (const float*)d_in[9];
    const float* b2   = (const float*)d_in[10];
    const float* gamma= (const float*)d_in[11];
    const float* beta = (const float*)d_in[12];
    float* out = (float*)d_out;

    char* ws = (char*)d_ws;
    float* W1f = (float*)ws; ws += (size_t)256*4*9*4;
    float* b1f = (float*)ws; ws += 1024;
    short* U1p = (short*)ws; ws += (size_t)147456*2;
    short* W2p = (short*)ws; ws += (size_t)147456*2;
    short* U2p = (short*)ws; ws += (size_t)147456*2;
    float* sums= (float*)ws; ws += 1024;
    float* coef= (float*)ws; ws += 1024;
    float* cbuf= (float*)ws; ws += (size_t)Bn*Fh*HWp*4;
    bf16*  h0b = (bf16*)ws; ws += (size_t)Bn*Fh*HWp*2;
    bf16*  hdb = (bf16*)ws; ws += (size_t)2*Bn*Fh*HWp*2;
    bf16*  x1  = (bf16*)ws; ws += (size_t)Bn*Tn*Fh*HWp*2;     // [t][b][p][fo]
    short* zx  = (short*)ws; ws += (size_t)Bn*Tn*256*HWp*2;   // [b][t][fo][p][g]

    const long nImg = (long)Bn*Fh*HWp;
    const long xOff = (long)Bn*Tn*Fh*HWp;
    int nImgB = (int)((nImg+255)/256);

    perm_w_kernel<<<(256*4*9+255)/256, 256, 0, stream>>>(W1, W1f, 4);
    perm_bias_kernel<<<1,256,0,stream>>>(b1, b1f);
    pack_w_kernel<<<576,256,0,stream>>>(U1, U1p);
    pack_w_kernel<<<576,256,0,stream>>>(W2, W2p);
    pack_w_kernel<<<576,256,0,stream>>>(U2, U2p);

    dim3 rgrid(Hd, Bn, 2);
    const long zbstr = (long)Tn*ZT;

    // ---- layer 1 ----
    dim3 zgrid1((HWp+255)/256, 64, Bn*Tn);
    zx1_kernel<<<zgrid1,256,0,stream>>>(xin, W1f, b1f, zx);
    copy_f32_kernel<<<nImgB,256,0,stream>>>(c1_0, cbuf, (int)nImg);
    h0cl_kernel<<<nImgB,256,0,stream>>>(h1_0, h0b);
    for (int t = 0; t < Tn; ++t){
        const bf16* hp = (t==0) ? h0b : x1 + (long)(t-1)*Bn*sHT;
        bf16* ho = x1 + (long)t*Bn*sHT;
        if (t == Tn-1)
            rec_step<true><<<rgrid,128,0,stream>>>(hp, sHT, U1p,
                zx + (long)t*ZT, zbstr, cbuf, ho, out + xOff, sHT);
        else
            rec_step<false><<<rgrid,128,0,stream>>>(hp, sHT, U1p,
                zx + (long)t*ZT, zbstr, cbuf, ho, nullptr, 0);
    }
    copy_f32_kernel<<<nImgB,256,0,stream>>>(cbuf, out + xOff + nImg, (int)nImg);

    // ---- BatchNorm (in-place on x1, channel-last) ----
    hipMemsetAsync(sums, 0, 640, stream);
    bn_sum_cl<<<BN_GRID,256,0,stream>>>((const short*)x1, sums);
    bn_coef_kernel<<<1,80,0,stream>>>(sums, gamma, beta, coef);
    bn_apply_cl<<<BN_GRID,256,0,stream>>>((short*)x1, coef);

    // ---- layer 2 ----
    dim3 zgrid2(Hd, Bn*Tn);
    zx_mfma<<<zgrid2,256,0,stream>>>(x1, W2p, b2, zx);
    copy_f32_kernel<<<nImgB,256,0,stream>>>(c2_0, cbuf, (int)nImg);
    h0cl_kernel<<<nImgB,256,0,stream>>>(h2_0, h0b);
    for (int t = 0; t < Tn; ++t){
        const bf16* hp = (t==0) ? h0b : hdb + (long)((t-1)&1)*Bn*sHT;
        bf16* ho = hdb + (long)(t&1)*Bn*sHT;
        rec_step<true><<<rgrid,128,0,stream>>>(hp, sHT, U2p,
            zx + (long)t*ZT, zbstr, cbuf, ho, out + (long)t*sHT, (long)Tn*sHT);
    }
    copy_h_f32_kernel<<<nImgB,256,0,stream>>>(out + (long)(Tn-1)*sHT, (long)Tn*sHT, out + xOff + 2*nImg);
    copy_f32_kernel<<<nImgB,256,0,stream>>>(cbuf, out + xOff + 3*nImg, (int)nImg);
}